// Round 1
// baseline (2605.582 us; speedup 1.0000x reference)
//
#include <hip/hip_runtime.h>
#include <hip/hip_runtime_api.h>
#include <math.h>

#define NBATCH 2
#define QQ     131072
#define HH     64
#define WWID   2048
#define CC     64
#define HWSZ   (HH*WWID)   /* 131072 = 2^17 */

constexpr int ROWS = 64;      // rows per block
constexpr int ASTR = 260;     // activation row stride (floats), 260 % 4 == 0 (16B-aligned rows)
constexpr int KCH  = 32;      // K-chunk for weight staging

// LDS layout (in floats)
constexpr int OFF_A   = 0;                   // A[64][260]
constexpr int OFF_W   = ROWS * ASTR;         // Wc[32][256]
constexpr int OFF_TAP = OFF_W + KCH * 256;   // tap[64][4] (int)
constexpr int OFF_PXY = OFF_TAP + ROWS * 4;  // pxy[64][4]
constexpr int LDSF    = OFF_PXY + ROWS * 4;  // total = 25344 floats = 101376 B

// ---------------------------------------------------------------------------
// Prep: feat NCHW -> NHWC into ws, and xy = sqrt(d1^2 + d2^2)
// ---------------------------------------------------------------------------
__global__ __launch_bounds__(256) void prep_kernel(
    const float* __restrict__ depth, const float* __restrict__ feat,
    float* __restrict__ nhwc, float* __restrict__ xy)
{
    const int idx = blockIdx.x * 256 + threadIdx.x;  // (b,y,x) flat, total NBATCH*HWSZ
    const int b   = idx >> 17;
    const int yx  = idx & (HWSZ - 1);

    const float d1 = depth[(b * 3 + 1) * HWSZ + yx];
    const float d2 = depth[(b * 3 + 2) * HWSZ + yx];
    xy[idx] = sqrtf(d1 * d1 + d2 * d2);

    const float* fp = feat + (size_t)b * CC * HWSZ + yx;  // stride HWSZ between channels
    float* op = nhwc + (size_t)idx * CC;
    #pragma unroll
    for (int c = 0; c < CC; c += 4) {
        float4 v;
        v.x = fp[(size_t)(c + 0) * HWSZ];
        v.y = fp[(size_t)(c + 1) * HWSZ];
        v.z = fp[(size_t)(c + 2) * HWSZ];
        v.w = fp[(size_t)(c + 3) * HWSZ];
        *(float4*)(op + c) = v;
    }
}

// ---------------------------------------------------------------------------
// Generic dense layer on the block's 64-row activation tile in LDS.
// Thread (rg=tid>>5, cg=tid&31) computes an 8-row x (N/32)-col register tile.
// Weights streamed global->LDS in 32-row K-chunks.
// ---------------------------------------------------------------------------
template <int K, int N, bool RELU>
__device__ __forceinline__ void dense_layer(
    float* __restrict__ sA, float* __restrict__ sW,
    const float* __restrict__ Wg, const float* __restrict__ Bg, int tid)
{
    constexpr int CT = N / 32;                 // cols per thread
    constexpr int KN = (K < KCH) ? K : KCH;    // chunk height
    const int rg = tid >> 5, cg = tid & 31;

    float acc[8][CT];
    #pragma unroll
    for (int r = 0; r < 8; ++r)
        #pragma unroll
        for (int c = 0; c < CT; ++c) acc[r][c] = 0.f;

    for (int kc = 0; kc < K; kc += KCH) {
        __syncthreads();   // previous users of sW done; prior sA writes ordered
        {   // stage W[kc:kc+KN][0:N] -> sW (coalesced float4)
            const float4* src = (const float4*)(Wg + kc * N);
            float4* dst = (float4*)sW;
            for (int i = tid; i < KN * N / 4; i += 256) dst[i] = src[i];
        }
        __syncthreads();

        #pragma unroll
        for (int k4 = 0; k4 < KN; k4 += 4) {
            float4 av[8];
            #pragma unroll
            for (int r = 0; r < 8; ++r)
                av[r] = *(const float4*)&sA[(rg * 8 + r) * ASTR + kc + k4];
            #pragma unroll
            for (int ki = 0; ki < 4; ++ki) {
                float wv[CT];
                #pragma unroll
                for (int c = 0; c < CT; ++c)
                    wv[c] = sW[(k4 + ki) * N + cg * CT + c];
                #pragma unroll
                for (int r = 0; r < 8; ++r) {
                    const float a = (ki == 0) ? av[r].x : (ki == 1) ? av[r].y
                                   : (ki == 2) ? av[r].z : av[r].w;
                    #pragma unroll
                    for (int c = 0; c < CT; ++c)
                        acc[r][c] = fmaf(a, wv[c], acc[r][c]);
                }
            }
        }
    }
    __syncthreads();   // all reads of sA complete before overwrite
    #pragma unroll
    for (int c = 0; c < CT; ++c) {
        const float bias = Bg[cg * CT + c];
        #pragma unroll
        for (int r = 0; r < 8; ++r) {
            float v = acc[r][c] + bias;
            if (RELU) v = fmaxf(v, 0.f);
            sA[(rg * 8 + r) * ASTR + cg * CT + c] = v;
        }
    }
    __syncthreads();
}

// ---------------------------------------------------------------------------
// Fused kernel: taps + PE MLP + gather-add + encoder MLP + softmax + output
// ---------------------------------------------------------------------------
template <bool USE_WS>
__global__ __launch_bounds__(256, 1) void fused_kernel(
    const float* __restrict__ depth, const float* __restrict__ feat,
    const float* __restrict__ coord,
    const float* __restrict__ pw0, const float* __restrict__ pb0,
    const float* __restrict__ pw1, const float* __restrict__ pb1,
    const float* __restrict__ pw2, const float* __restrict__ pb2,
    const float* __restrict__ ew0, const float* __restrict__ eb0,
    const float* __restrict__ ew1, const float* __restrict__ eb1,
    const float* __restrict__ ew2, const float* __restrict__ eb2,
    const float* __restrict__ ew3, const float* __restrict__ eb3,
    const float* __restrict__ nhwc, const float* __restrict__ xyws,
    float* __restrict__ out)
{
    extern __shared__ float lds[];
    float* sA   = lds + OFF_A;
    float* sW   = lds + OFF_W;
    int*   sTap = (int*)(lds + OFF_TAP);
    float* sPxy = lds + OFF_PXY;

    const int tid  = threadIdx.x;
    const int row0 = blockIdx.x * ROWS;
    const int b    = row0 / QQ;   // uniform per block (QQ % ROWS == 0)

    // ---- setup: one (row, tap) per thread; contraction OFF so fp32 tap
    //      rounding matches the numpy fp32 reference exactly ----
    {
        #pragma clang fp contract(off)
        const int r = tid >> 2, s = tid & 3;
        const int row = row0 + r;
        const float cy = coord[row * 2 + 0];
        const float cx = coord[row * 2 + 1];
        const float offy = (s < 2) ? -1.f : 1.f;
        const float offx = (s & 1) ? 1.f : -1.f;
        const float rx = 1.f / (float)HH, ry = 1.f / (float)WWID;
        float ccy = cy + (offy * rx + 1e-6f);
        float ccx = cx + (offx * ry + 1e-6f);
        ccy = fminf(fmaxf(ccy, -1.f + 1e-6f), 1.f - 1e-6f);
        ccx = fminf(fmaxf(ccx, -1.f + 1e-6f), 1.f - 1e-6f);
        int iy = (int)rintf(((ccy + 1.f) * (float)HH - 1.f) * 0.5f);
        int ix = (int)rintf(((ccx + 1.f) * (float)WWID - 1.f) * 0.5f);
        iy = min(max(iy, 0), HH - 1);
        ix = min(max(ix, 0), WWID - 1);
        const float qcy = -1.f + (2.f * (float)iy + 1.f) / (float)HH;
        const float qcx = -1.f + (2.f * (float)ix + 1.f) / (float)WWID;
        sA[r * ASTR + s * 2 + 0] = (cy - qcy) * (float)HH;
        sA[r * ASTR + s * 2 + 1] = (cx - qcx) * (float)WWID;
        const int tap = iy * WWID + ix;
        sTap[r * 4 + s] = tap;
        float px;
        if (USE_WS) {
            px = xyws[b * HWSZ + tap];
        } else {
            const float d1 = depth[(b * 3 + 1) * HWSZ + tap];
            const float d2 = depth[(b * 3 + 2) * HWSZ + tap];
            px = sqrtf(d1 * d1 + d2 * d2);
        }
        sPxy[r * 4 + s] = px;
    }
    __syncthreads();

    // ---- PE MLP on rel coords (cols 0..7 of sA) ----
    dense_layer<8,   64, true >(sA, sW, pw0, pb0, tid);
    dense_layer<64, 128, true >(sA, sW, pw1, pb1, tid);
    dense_layer<128,256, false>(sA, sW, pw2, pb2, tid);

    // ---- gather-add q_feat: A[r][s*64+c] += feat[b, c, iy, ix] ----
    {
        const int r = tid >> 2, s = tid & 3;
        const int tap = sTap[r * 4 + s];
        if (USE_WS) {
            const float4* src = (const float4*)(nhwc + ((size_t)b * HWSZ + tap) * CC);
            float4* dst = (float4*)&sA[r * ASTR + s * 64];
            #pragma unroll
            for (int c4 = 0; c4 < 16; ++c4) {
                float4 v = src[c4];
                float4 d = dst[c4];
                d.x += v.x; d.y += v.y; d.z += v.z; d.w += v.w;
                dst[c4] = d;
            }
        } else {
            #pragma unroll 4
            for (int c = 0; c < CC; ++c)
                sA[r * ASTR + s * 64 + c] += feat[(size_t)(b * CC + c) * HWSZ + tap];
        }
    }
    __syncthreads();

    // ---- encoder MLP ----
    dense_layer<256, 256, true>(sA, sW, ew0, eb0, tid);
    dense_layer<256, 128, true>(sA, sW, ew1, eb1, tid);
    dense_layer<128,  64, true>(sA, sW, ew2, eb2, tid);

    // ---- final 64->4, softmax, weighted sum with pred_xy ----
    if (tid < 64) ((float4*)sW)[tid] = ((const float4*)ew3)[tid];  // 64x4 weights
    __syncthreads();
    if (tid < 64) {
        const int r = tid;
        float l0 = eb3[0], l1 = eb3[1], l2 = eb3[2], l3 = eb3[3];
        #pragma unroll 8
        for (int k = 0; k < 64; ++k) {
            const float a = sA[r * ASTR + k];
            const float4 w = ((const float4*)sW)[k];
            l0 = fmaf(a, w.x, l0);
            l1 = fmaf(a, w.y, l1);
            l2 = fmaf(a, w.z, l2);
            l3 = fmaf(a, w.w, l3);
        }
        const float m  = fmaxf(fmaxf(l0, l1), fmaxf(l2, l3));
        const float e0 = expf(l0 - m), e1 = expf(l1 - m);
        const float e2 = expf(l2 - m), e3 = expf(l3 - m);
        const float inv = 1.f / (e0 + e1 + e2 + e3);
        const float o = (sPxy[r * 4 + 0] * e0 + sPxy[r * 4 + 1] * e1 +
                         sPxy[r * 4 + 2] * e2 + sPxy[r * 4 + 3] * e3) * inv;
        out[row0 + r] = o;
    }
}

// ---------------------------------------------------------------------------
extern "C" void kernel_launch(void* const* d_in, const int* in_sizes, int n_in,
                              void* d_out, int out_size, void* d_ws, size_t ws_size,
                              hipStream_t stream)
{
    const float* depth = (const float*)d_in[0];
    const float* feat  = (const float*)d_in[1];
    const float* coord = (const float*)d_in[2];
    const float* pw0 = (const float*)d_in[3],  *pb0 = (const float*)d_in[4];
    const float* pw1 = (const float*)d_in[5],  *pb1 = (const float*)d_in[6];
    const float* pw2 = (const float*)d_in[7],  *pb2 = (const float*)d_in[8];
    const float* ew0 = (const float*)d_in[9],  *eb0 = (const float*)d_in[10];
    const float* ew1 = (const float*)d_in[11], *eb1 = (const float*)d_in[12];
    const float* ew2 = (const float*)d_in[13], *eb2 = (const float*)d_in[14];
    const float* ew3 = (const float*)d_in[15], *eb3 = (const float*)d_in[16];
    float* out = (float*)d_out;

    const size_t need = ((size_t)NBATCH * HWSZ * CC + (size_t)NBATCH * HWSZ) * sizeof(float);
    const bool use_ws = (ws_size >= need);

    float* nhwc = (float*)d_ws;
    float* xyws = nhwc + (size_t)NBATCH * HWSZ * CC;

    const size_t lds_bytes = (size_t)LDSF * sizeof(float);
    const int nblocks = (NBATCH * QQ) / ROWS;   // 4096

    if (use_ws) {
        prep_kernel<<<(NBATCH * HWSZ) / 256, 256, 0, stream>>>(depth, feat, nhwc, xyws);
        hipFuncSetAttribute((const void*)fused_kernel<true>,
                            hipFuncAttributeMaxDynamicSharedMemorySize, (int)lds_bytes);
        fused_kernel<true><<<nblocks, 256, lds_bytes, stream>>>(
            depth, feat, coord, pw0, pb0, pw1, pb1, pw2, pb2,
            ew0, eb0, ew1, eb1, ew2, eb2, ew3, eb3, nhwc, xyws, out);
    } else {
        hipFuncSetAttribute((const void*)fused_kernel<false>,
                            hipFuncAttributeMaxDynamicSharedMemorySize, (int)lds_bytes);
        fused_kernel<false><<<nblocks, 256, lds_bytes, stream>>>(
            depth, feat, coord, pw0, pb0, pw1, pb1, pw2, pb2,
            ew0, eb0, ew1, eb1, ew2, eb2, ew3, eb3, nhwc, xyws, out);
    }
}

// Round 2
// 270.067 us; speedup vs baseline: 9.6479x; 9.6479x over previous
//
#include <hip/hip_runtime.h>
#include <hip/hip_runtime_api.h>
#include <math.h>

#define NBATCH 2
#define QQ     131072
#define HH     64
#define WWID   2048
#define CC     64
#define HWSZ   (HH*WWID)   /* 131072 = 2^17 */

constexpr int ROWS    = 128;   // rows per block
constexpr int THREADS = 1024;  // 16 waves
constexpr int ASTR_B  = 528;   // A row stride bytes (264 bf16; 132 dwords -> 4/32 bank walk)
constexpr int WSTR_B  = 144;   // staged-W row stride bytes (72 bf16)

// dynamic-LDS byte offsets
constexpr int OFF_A   = 0;              // A[128][264] bf16 = 67584 B
constexpr int OFF_W   = 67584;          // Wc[256][72]  bf16 = 36864 B
constexpr int OFF_TAP = OFF_W + 36864;  // tap[128][4] int   =  2048 B
constexpr int OFF_PXY = OFF_TAP + 2048; // pxy[128][4] f32   =  2048 B
constexpr int OFF_E3  = OFF_PXY + 2048; // ew3 64x4 f32      =  1024 B
constexpr int LDS_BYTES = OFF_E3 + 1024;  // 109568 B -> 1 block/CU, 16 waves

// transposed bf16 weight offsets in elements (Wt[N][Kp], Kp = K rounded to 64)
constexpr int WOFF_PE0 = 0;       // 64 x 64
constexpr int WOFF_PE1 = 4096;    // 128 x 64
constexpr int WOFF_PE2 = 12288;   // 256 x 128
constexpr int WOFF_E0  = 45056;   // 256 x 256
constexpr int WOFF_E1  = 110592;  // 128 x 256
constexpr int WOFF_E2  = 143360;  // 64 x 128
constexpr int WTOTAL   = 151552;

typedef __attribute__((ext_vector_type(8))) short bf16x8;
typedef __attribute__((ext_vector_type(4))) float f32x4;

__device__ __forceinline__ ushort f2bf(float f) {
    union { float f; unsigned u; } x; x.f = f;
    unsigned r = x.u + 0x7fffu + ((x.u >> 16) & 1u);   // RNE
    return (ushort)(r >> 16);
}
__device__ __forceinline__ float bf2f(ushort h) {
    union { unsigned u; float f; } x; x.u = ((unsigned)h) << 16;
    return x.f;
}

// ---------------------------------------------------------------------------
// Weight prep: fp32 [K][N] -> bf16 transposed [N][Kp], zero-padded K -> Kp
// ---------------------------------------------------------------------------
struct WDesc { const float* src; int K; int N; int kshift; };  // Kp = 1<<kshift
struct WPack { WDesc d[6]; };

__global__ __launch_bounds__(256) void prep_weights(WPack p, ushort* __restrict__ dst)
{
    int e = blockIdx.x * 256 + threadIdx.x;
    int off = 0;
    #pragma unroll
    for (int L = 0; L < 6; ++L) {
        const int Kp = 1 << p.d[L].kshift;
        const int sz = p.d[L].N * Kp;
        if (e < sz) {
            const int n = e >> p.d[L].kshift;
            const int k = e & (Kp - 1);
            const float v = (k < p.d[L].K) ? p.d[L].src[(size_t)k * p.d[L].N + n] : 0.f;
            dst[off + e] = f2bf(v);
            return;
        }
        e -= sz; off += sz;
    }
}

// ---------------------------------------------------------------------------
// Feat prep: NCHW f32 -> NHWC bf16, plus xy = sqrt(d1^2+d2^2)
// ---------------------------------------------------------------------------
__global__ __launch_bounds__(256) void prep_feat(
    const float* __restrict__ depth, const float* __restrict__ feat,
    ushort* __restrict__ nhwc, float* __restrict__ xy)
{
    const int idx = blockIdx.x * 256 + threadIdx.x;
    const int b   = idx >> 17;
    const int yx  = idx & (HWSZ - 1);

    const float d1 = depth[(b * 3 + 1) * HWSZ + yx];
    const float d2 = depth[(b * 3 + 2) * HWSZ + yx];
    xy[idx] = sqrtf(d1 * d1 + d2 * d2);

    const float* fp = feat + (size_t)b * CC * HWSZ + yx;
    ushort* op = nhwc + (size_t)idx * CC;
    #pragma unroll
    for (int c = 0; c < CC; c += 8) {
        union { uint4 v; ushort u[8]; } t;
        #pragma unroll
        for (int j = 0; j < 8; ++j) t.u[j] = f2bf(fp[(size_t)(c + j) * HWSZ]);
        *(uint4*)(op + c) = t.v;
    }
}

// ---------------------------------------------------------------------------
// One dense layer, in place on A[128][...] (bf16, LDS). 16 waves = 4M x 4N.
// Wave tile: 32 rows x N/4 cols via 16x16x32 bf16 MFMA. Weights Wt[N][K] bf16
// (pre-transposed) streamed to LDS in 64-wide K chunks.
// ---------------------------------------------------------------------------
template <int K, int N, bool RELU>
__device__ __forceinline__ void dense_layer(
    char* __restrict__ lds, const ushort* __restrict__ Wt,
    const float* __restrict__ Bg, int tid)
{
    constexpr int TN = N / 64;            // 16-col tiles per wave (N/4 cols)
    char* sA = lds + OFF_A;
    char* sW = lds + OFF_W;

    const int lane = tid & 63, wid = tid >> 6;
    const int wm = wid >> 2, wn = wid & 3;
    const int row0 = wm * 32;
    const int col0 = wn * (N / 4);
    const int lrow = lane & 15;
    const int lk8  = (lane >> 4) * 8;

    f32x4 acc[2][TN];
    #pragma unroll
    for (int tm = 0; tm < 2; ++tm)
        #pragma unroll
        for (int tn = 0; tn < TN; ++tn) acc[tm][tn] = (f32x4){0.f, 0.f, 0.f, 0.f};

    #pragma unroll
    for (int kc = 0; kc < K; kc += 64) {
        __syncthreads();   // prior users of sW / prior layer writes done
        {   // stage Wt[0:N][kc:kc+64) -> sW, row stride 144 B
            constexpr int SEGS = N * 8;   // 16 B segments
            for (int i = tid; i < SEGS; i += THREADS) {
                const int n = i >> 3, s = i & 7;
                *(uint4*)(sW + n * WSTR_B + s * 16) =
                    *(const uint4*)(Wt + (size_t)n * K + kc + s * 8);
            }
        }
        __syncthreads();

        #pragma unroll
        for (int ks = 0; ks < 64; ks += 32) {
            const bf16x8 a0 = *(const bf16x8*)(sA + (row0 +      lrow) * ASTR_B + (kc + ks + lk8) * 2);
            const bf16x8 a1 = *(const bf16x8*)(sA + (row0 + 16 + lrow) * ASTR_B + (kc + ks + lk8) * 2);
            #pragma unroll
            for (int tn = 0; tn < TN; ++tn) {
                const bf16x8 bw = *(const bf16x8*)(sW + (col0 + tn * 16 + lrow) * WSTR_B + (ks + lk8) * 2);
                acc[0][tn] = __builtin_amdgcn_mfma_f32_16x16x32_bf16(a0, bw, acc[0][tn], 0, 0, 0);
                acc[1][tn] = __builtin_amdgcn_mfma_f32_16x16x32_bf16(a1, bw, acc[1][tn], 0, 0, 0);
            }
        }
    }
    __syncthreads();   // ALL waves done reading A before anyone overwrites it

    #pragma unroll
    for (int tn = 0; tn < TN; ++tn) {
        const int col = col0 + tn * 16 + lrow;
        const float bias = Bg[col];
        #pragma unroll
        for (int tm = 0; tm < 2; ++tm) {
            #pragma unroll
            for (int j = 0; j < 4; ++j) {
                float v = acc[tm][tn][j] + bias;
                if (RELU) v = fmaxf(v, 0.f);
                const int row = row0 + tm * 16 + (lane >> 4) * 4 + j;
                *(ushort*)(sA + row * ASTR_B + col * 2) = f2bf(v);
            }
        }
    }
    __syncthreads();
}

// ---------------------------------------------------------------------------
// Fused: taps + PE MLP + gather-add + encoder MLP + softmax + output
// ---------------------------------------------------------------------------
template <bool USE_WS>
__global__ __launch_bounds__(1024, 1) void fused_kernel(
    const float* __restrict__ depth, const float* __restrict__ feat,
    const float* __restrict__ coord,
    const float* __restrict__ pb0, const float* __restrict__ pb1,
    const float* __restrict__ pb2,
    const float* __restrict__ eb0, const float* __restrict__ eb1,
    const float* __restrict__ eb2,
    const float* __restrict__ ew3, const float* __restrict__ eb3,
    const ushort* __restrict__ wt,
    const ushort* __restrict__ nhwc, const float* __restrict__ xyws,
    float* __restrict__ out)
{
    extern __shared__ char lds[];
    char*  sA   = lds + OFF_A;
    int*   sTap = (int*)(lds + OFF_TAP);
    float* sPxy = (float*)(lds + OFF_PXY);
    float* sE3  = (float*)(lds + OFF_E3);

    const int tid  = threadIdx.x;
    const int row0 = blockIdx.x * ROWS;
    const int b    = row0 >> 17;   // QQ = 2^17, ROWS | QQ

    // stage final-layer weights (64x4 f32); region untouched until the end
    if (tid < 256) sE3[tid] = ew3[tid];

    // zero A cols 0..63 (pe0 K padded 8->64; avoids NaN*0 from stale LDS)
    {
        const int r = tid >> 3, c8 = tid & 7;
        uint4 z; z.x = z.y = z.z = z.w = 0u;
        *(uint4*)(sA + r * ASTR_B + c8 * 16) = z;
    }
    __syncthreads();

    // taps + rel coords + pred_xy; fp32, contraction OFF (match numpy rounding)
    if (tid < 512) {
        #pragma clang fp contract(off)
        const int r = tid >> 2, s = tid & 3;
        const int row = row0 + r;
        const float cy = coord[row * 2 + 0];
        const float cx = coord[row * 2 + 1];
        const float offy = (s < 2) ? -1.f : 1.f;
        const float offx = (s & 1) ? 1.f : -1.f;
        const float rx = 1.f / (float)HH, ry = 1.f / (float)WWID;
        float ccy = cy + (offy * rx + 1e-6f);
        float ccx = cx + (offx * ry + 1e-6f);
        ccy = fminf(fmaxf(ccy, -1.f + 1e-6f), 1.f - 1e-6f);
        ccx = fminf(fmaxf(ccx, -1.f + 1e-6f), 1.f - 1e-6f);
        int iy = (int)rintf(((ccy + 1.f) * (float)HH - 1.f) * 0.5f);
        int ix = (int)rintf(((ccx + 1.f) * (float)WWID - 1.f) * 0.5f);
        iy = min(max(iy, 0), HH - 1);
        ix = min(max(ix, 0), WWID - 1);
        const float qcy = -1.f + (2.f * (float)iy + 1.f) / (float)HH;
        const float qcx = -1.f + (2.f * (float)ix + 1.f) / (float)WWID;
        ushort* relp = (ushort*)(sA + r * ASTR_B);
        relp[s * 2 + 0] = f2bf((cy - qcy) * (float)HH);
        relp[s * 2 + 1] = f2bf((cx - qcx) * (float)WWID);
        const int tap = iy * WWID + ix;
        sTap[r * 4 + s] = tap;
        float px;
        if (USE_WS) {
            px = xyws[b * HWSZ + tap];
        } else {
            const float d1 = depth[(b * 3 + 1) * HWSZ + tap];
            const float d2 = depth[(b * 3 + 2) * HWSZ + tap];
            px = sqrtf(d1 * d1 + d2 * d2);
        }
        sPxy[r * 4 + s] = px;
    }
    __syncthreads();

    // PE MLP (rel coords in A cols 0..7, zero-padded to 64)
    dense_layer<64,  64,  true >(lds, wt + WOFF_PE0, pb0, tid);
    dense_layer<64,  128, true >(lds, wt + WOFF_PE1, pb1, tid);
    dense_layer<128, 256, false>(lds, wt + WOFF_PE2, pb2, tid);

    // gather-add q_feat: A[r][s*64+c] += feat[b,c,tap]
    {
        const int r = tid >> 3, h = tid & 7;
        const int s = h >> 1, half = h & 1;
        const int tap = sTap[r * 4 + s];
        char* dst = sA + r * ASTR_B + (s * CC + half * 32) * 2;
        if (USE_WS) {
            const ushort* src = nhwc + ((size_t)b * HWSZ + tap) * CC + half * 32;
            #pragma unroll
            for (int g = 0; g < 4; ++g) {
                union { uint4 v; ushort u[8]; } a, d, o;
                a.v = *(const uint4*)(src + g * 8);
                d.v = *(uint4*)(dst + g * 16);
                #pragma unroll
                for (int j = 0; j < 8; ++j)
                    o.u[j] = f2bf(bf2f(a.u[j]) + bf2f(d.u[j]));
                *(uint4*)(dst + g * 16) = o.v;
            }
        } else {
            const float* fp = feat + (size_t)b * CC * HWSZ + tap;
            #pragma unroll 8
            for (int c = 0; c < 32; ++c) {
                const int ch = half * 32 + c;
                ushort* p = (ushort*)(dst + c * 2);
                *p = f2bf(bf2f(*p) + fp[(size_t)ch * HWSZ]);
            }
        }
    }
    __syncthreads();

    // encoder MLP
    dense_layer<256, 256, true>(lds, wt + WOFF_E0, eb0, tid);
    dense_layer<256, 128, true>(lds, wt + WOFF_E1, eb1, tid);
    dense_layer<128, 64,  true>(lds, wt + WOFF_E2, eb2, tid);

    // final 64->4, softmax, weighted sum with pred_xy
    if (tid < ROWS) {
        const int r = tid;
        float l0 = eb3[0], l1 = eb3[1], l2 = eb3[2], l3 = eb3[3];
        #pragma unroll 8
        for (int k = 0; k < 64; ++k) {
            const float a = bf2f(*(const ushort*)(sA + r * ASTR_B + k * 2));
            const float4 w = ((const float4*)sE3)[k];
            l0 = fmaf(a, w.x, l0);
            l1 = fmaf(a, w.y, l1);
            l2 = fmaf(a, w.z, l2);
            l3 = fmaf(a, w.w, l3);
        }
        const float m  = fmaxf(fmaxf(l0, l1), fmaxf(l2, l3));
        const float e0 = expf(l0 - m), e1 = expf(l1 - m);
        const float e2 = expf(l2 - m), e3 = expf(l3 - m);
        const float inv = 1.f / (e0 + e1 + e2 + e3);
        const float o = (sPxy[r * 4 + 0] * e0 + sPxy[r * 4 + 1] * e1 +
                         sPxy[r * 4 + 2] * e2 + sPxy[r * 4 + 3] * e3) * inv;
        out[row0 + r] = o;
    }
}

// ---------------------------------------------------------------------------
extern "C" void kernel_launch(void* const* d_in, const int* in_sizes, int n_in,
                              void* d_out, int out_size, void* d_ws, size_t ws_size,
                              hipStream_t stream)
{
    const float* depth = (const float*)d_in[0];
    const float* feat  = (const float*)d_in[1];
    const float* coord = (const float*)d_in[2];
    const float* pw0 = (const float*)d_in[3],  *pb0 = (const float*)d_in[4];
    const float* pw1 = (const float*)d_in[5],  *pb1 = (const float*)d_in[6];
    const float* pw2 = (const float*)d_in[7],  *pb2 = (const float*)d_in[8];
    const float* ew0 = (const float*)d_in[9],  *eb0 = (const float*)d_in[10];
    const float* ew1 = (const float*)d_in[11], *eb1 = (const float*)d_in[12];
    const float* ew2 = (const float*)d_in[13], *eb2 = (const float*)d_in[14];
    const float* ew3 = (const float*)d_in[15], *eb3 = (const float*)d_in[16];
    float* out = (float*)d_out;

    const size_t nhwc_bytes = (size_t)NBATCH * HWSZ * CC * 2;
    const size_t xy_bytes   = (size_t)NBATCH * HWSZ * 4;
    const size_t wt_bytes   = (size_t)WTOTAL * 2;
    const bool use_ws = (ws_size >= nhwc_bytes + xy_bytes + wt_bytes);

    ushort* nhwc = (ushort*)d_ws;
    float*  xyws = (float*)((char*)d_ws + nhwc_bytes);
    ushort* wt   = use_ws ? (ushort*)((char*)d_ws + nhwc_bytes + xy_bytes)
                          : (ushort*)d_ws;

    WPack pack;
    pack.d[0] = { pw0, 8,   64,  6 };
    pack.d[1] = { pw1, 64,  128, 6 };
    pack.d[2] = { pw2, 128, 256, 7 };
    pack.d[3] = { ew0, 256, 256, 8 };
    pack.d[4] = { ew1, 256, 128, 8 };
    pack.d[5] = { ew2, 128, 64,  7 };
    prep_weights<<<WTOTAL / 256, 256, 0, stream>>>(pack, wt);

    const int nblocks = (NBATCH * QQ) / ROWS;   // 2048

    if (use_ws) {
        prep_feat<<<(NBATCH * HWSZ) / 256, 256, 0, stream>>>(depth, feat, nhwc, xyws);
        hipFuncSetAttribute((const void*)fused_kernel<true>,
                            hipFuncAttributeMaxDynamicSharedMemorySize, LDS_BYTES);
        fused_kernel<true><<<nblocks, THREADS, LDS_BYTES, stream>>>(
            depth, feat, coord, pb0, pb1, pb2, eb0, eb1, eb2, ew3, eb3,
            wt, nhwc, xyws, out);
    } else {
        hipFuncSetAttribute((const void*)fused_kernel<false>,
                            hipFuncAttributeMaxDynamicSharedMemorySize, LDS_BYTES);
        fused_kernel<false><<<nblocks, THREADS, LDS_BYTES, stream>>>(
            depth, feat, coord, pb0, pb1, pb2, eb0, eb1, eb2, ew3, eb3,
            wt, nhwc, xyws, out);
    }
}